// Round 1
// baseline (422.683 us; speedup 1.0000x reference)
//
#include <hip/hip_runtime.h>

// dv = (-v + segment_sum(w * relu(v[src]) * tp[ntype[src]], dst) + stim + Vrest) / tau
// N_NODES = 500000, N_EDGES = 16000000. edge_index flat: src=[0,E), dst=[E,2E).
//
// R1: agent-scope fp32 atomics -> memory-side RMW wall (~20G/s) -> 785us.
// R2: counting sort, direct 4B random writes -> 7x write amp -> 489us scatter.
// R4: LDS-staged bucket sort + coalesced bursts -> 241us scatter @ 19% occ.
// R5: 1024-thr scatter + prefix-derived hist -> 188us scatter.
// R7: wave-per-segment accum + dst-in-regs scatter -> 420us total.
// R8: private slices + lpref; scatter 144us but accum must merge 977
//     33.5-record segments/bucket (strided (s,e) loads, shfl, 52% lane util)
//     -> accum ~135us latency-bound. Total 420.8us.
// R9 (this): bucket-major global sort. Scatter copy-out reserves space in a
//     global per-bucket region via atomic cursor (wave-parallel, 489/block),
//     writes each LDS run as a ~134B burst (order within bucket irrelevant
//     for a sum). Accum reads ONE contiguous uint4-coalesced region per
//     bucket -- no lpref, no shfl merge. Slack = mean+2048 (+11 sigma);
//     impossible-overflow runs go to a spill list scanned by accum (1 load
//     when empty). Predicted: scatter ~150us (write amp 1.5x), accum ~35us.

#define BSHIFT 10
#define BSIZE  1024              // nodes per bucket
#define NBMAX  512               // > nb = ceil(500000/1024) = 489
#define GPB    4096              // int4 groups per scatter block = 16384 edges
#define EPB    (GPB * 4)
#define SPILL_CAP 131072

// ---------------- main path ----------------

__global__ void pre_g_kernel(const float* __restrict__ v,
                             const int* __restrict__ ntype,
                             const float* __restrict__ tp,
                             float* __restrict__ g,
                             unsigned* __restrict__ gcur,
                             int n, int nb) {
    int i = blockIdx.x * blockDim.x + threadIdx.x;
    if (i < n) {
        float x = v[i];
        x = x > 0.0f ? x : 0.0f;
        g[i] = x * tp[ntype[i]];
    }
    if (i <= nb) gcur[i] = 0u;   // gcur[0..nb-1] = bucket cursors, gcur[nb] = spill count
}

// grid = nblk, 1024 threads. Bins one 16K-edge chunk into per-bucket runs in
// LDS (dst in registers across both passes; scan via shfl), then copies each
// run to the bucket's global region at an atomically-reserved offset.
__global__ __launch_bounds__(1024, 8)
void scatter_kernel(const int* __restrict__ src,
                    const int* __restrict__ dst,
                    const float* __restrict__ w,
                    const float* __restrict__ g,
                    unsigned* __restrict__ bucketbuf,
                    unsigned* __restrict__ gcur,
                    uint2* __restrict__ spill,
                    int G, int n_edges, int nblk, int nb, int cap) {
    __shared__ unsigned stage[EPB];      // 64 KB
    __shared__ unsigned lstart[NBMAX];   // exclusive starts (2 KB)
    __shared__ unsigned lcur[NBMAX];     // working cursors   (2 KB)
    __shared__ unsigned gposs[NBMAX];    // global positions  (2 KB)
    __shared__ unsigned wsum[16];
    int blk = blockIdx.x, tid = threadIdx.x;
    int wid = tid >> 6, lane = tid & 63;
    bool last = (blk == nblk - 1);

    if (tid < NBMAX) lcur[tid] = 0;
    __syncthreads();

    const int4*   s4 = (const int4*)src;
    const int4*   d4 = (const int4*)dst;
    const float4* w4 = (const float4*)w;
    int gstart = blk * GPB;
    int gend = gstart + GPB; if (gend > G) gend = G;

    // pass 1: load dst groups into registers + local histogram
    int4 dreg[4];
    #pragma unroll
    for (int k = 0; k < 4; k++) {
        int i = gstart + tid + k * 1024;
        if (i < gend) {
            int4 d = d4[i];
            dreg[k] = d;
            atomicAdd(&lcur[((unsigned)d.x) >> BSHIFT], 1u);
            atomicAdd(&lcur[((unsigned)d.y) >> BSHIFT], 1u);
            atomicAdd(&lcur[((unsigned)d.z) >> BSHIFT], 1u);
            atomicAdd(&lcur[((unsigned)d.w) >> BSHIFT], 1u);
        }
    }
    if (last) {
        for (int i = G * 4 + tid; i < n_edges; i += 1024)
            atomicAdd(&lcur[((unsigned)dst[i]) >> BSHIFT], 1u);
    }
    __syncthreads();

    // exclusive scan over NBMAX=512 entries (first 8 waves hold counts):
    // wave-level shfl scan + cross-wave scan of 8 partials.
    unsigned cntv = (tid < NBMAX) ? lcur[tid] : 0u;
    unsigned inc = cntv;
    #pragma unroll
    for (int o = 1; o < 64; o <<= 1) {
        unsigned t = __shfl_up(inc, o, 64);
        if (lane >= o) inc += t;
    }
    if (lane == 63) wsum[wid] = inc;
    __syncthreads();
    if (tid < 64) {
        unsigned x = (lane < 16) ? wsum[lane] : 0u;
        unsigned xi = x;
        #pragma unroll
        for (int o = 1; o < 16; o <<= 1) {
            unsigned t = __shfl_up(xi, o, 64);
            if (lane >= o) xi += t;
        }
        if (lane < 16) wsum[lane] = xi - x;   // exclusive wave offsets
    }
    __syncthreads();
    if (tid < NBMAX) {
        unsigned excl = inc - cntv + wsum[wid];
        lstart[tid] = excl;
        lcur[tid] = excl;
    }
    __syncthreads();

    // pass 2: bin packed records (value top-22 bits | 10-bit local dst)
    #pragma unroll
    for (int k = 0; k < 4; k++) {
        int i = gstart + tid + k * 1024;
        if (i < gend) {
            int4 s = s4[i]; float4 wv = w4[i]; int4 d = dreg[k];
            {
                unsigned b = ((unsigned)d.x) >> BSHIFT;
                unsigned pos = atomicAdd(&lcur[b], 1u);
                stage[pos] = (__float_as_uint(wv.x * g[s.x]) & ~(unsigned)(BSIZE - 1)) |
                             ((unsigned)d.x & (BSIZE - 1));
            }
            {
                unsigned b = ((unsigned)d.y) >> BSHIFT;
                unsigned pos = atomicAdd(&lcur[b], 1u);
                stage[pos] = (__float_as_uint(wv.y * g[s.y]) & ~(unsigned)(BSIZE - 1)) |
                             ((unsigned)d.y & (BSIZE - 1));
            }
            {
                unsigned b = ((unsigned)d.z) >> BSHIFT;
                unsigned pos = atomicAdd(&lcur[b], 1u);
                stage[pos] = (__float_as_uint(wv.z * g[s.z]) & ~(unsigned)(BSIZE - 1)) |
                             ((unsigned)d.z & (BSIZE - 1));
            }
            {
                unsigned b = ((unsigned)d.w) >> BSHIFT;
                unsigned pos = atomicAdd(&lcur[b], 1u);
                stage[pos] = (__float_as_uint(wv.w * g[s.w]) & ~(unsigned)(BSIZE - 1)) |
                             ((unsigned)d.w & (BSIZE - 1));
            }
        }
    }
    if (last) {
        for (int i = G * 4 + tid; i < n_edges; i += 1024) {
            int dd = dst[i];
            unsigned b = ((unsigned)dd) >> BSHIFT;
            unsigned pos = atomicAdd(&lcur[b], 1u);
            stage[pos] = (__float_as_uint(w[i] * g[src[i]]) & ~(unsigned)(BSIZE - 1)) |
                         ((unsigned)dd & (BSIZE - 1));
        }
    }
    __syncthreads();

    // reserve global space per bucket (489 wave-parallel atomics)
    if (tid < nb) {
        unsigned len = lcur[tid] - lstart[tid];
        unsigned p = 0u;
        if (len) {
            p = atomicAdd(&gcur[tid], len);
            if (p + len > (unsigned)cap) {          // ~11-sigma event: spill run
                atomicSub(&gcur[tid], len);
                unsigned sp = atomicAdd(&gcur[nb], len);
                p = 0x80000000u | sp;
            }
        }
        gposs[tid] = p;
    }
    __syncthreads();

    // copy-out: wave per run, coalesced ~134B bursts to bucket-major regions
    for (int b = wid; b < nb; b += 16) {
        unsigned st  = lstart[b];
        unsigned len = lcur[b] - st;
        if (!len) continue;
        unsigned p = gposs[b];
        if (p & 0x80000000u) {
            unsigned sp = p & 0x7FFFFFFFu;
            for (unsigned j = lane; j < len; j += 64) {
                if (sp + j < SPILL_CAP) {
                    unsigned u = stage[st + j];
                    spill[sp + j] = make_uint2(((unsigned)b << BSHIFT) | (u & (BSIZE - 1u)),
                                               u & ~(unsigned)(BSIZE - 1));
                }
            }
        } else {
            unsigned* dp = bucketbuf + (size_t)b * (unsigned)cap + p;
            for (unsigned j = lane; j < len; j += 64)
                dp[j] = stage[st + j];
        }
    }
}

// grid = nb, 1024 threads. One contiguous uint4-coalesced region per bucket.
__global__ __launch_bounds__(1024, 2)
void accum_kernel(const unsigned* __restrict__ bucketbuf,
                  const unsigned* __restrict__ gcur,
                  const uint2* __restrict__ spill,
                  const float* __restrict__ v,
                  const float* __restrict__ stim,
                  const float* __restrict__ vrest,
                  const float* __restrict__ tau,
                  float* __restrict__ out,
                  int n_nodes, int nb, int cap) {
    __shared__ float acc[BSIZE];
    int b = blockIdx.x, tid = threadIdx.x;
    acc[tid] = 0.0f;
    __syncthreads();

    unsigned cnt = gcur[b];
    if (cnt > (unsigned)cap) cnt = (unsigned)cap;
    const unsigned* base = bucketbuf + (size_t)b * (unsigned)cap;
    const uint4* b4 = (const uint4*)base;
    unsigned nq = cnt >> 2;
    for (unsigned i = tid; i < nq; i += 1024) {
        uint4 u = b4[i];
        atomicAdd(&acc[u.x & (BSIZE - 1u)], __uint_as_float(u.x & ~(unsigned)(BSIZE - 1)));
        atomicAdd(&acc[u.y & (BSIZE - 1u)], __uint_as_float(u.y & ~(unsigned)(BSIZE - 1)));
        atomicAdd(&acc[u.z & (BSIZE - 1u)], __uint_as_float(u.z & ~(unsigned)(BSIZE - 1)));
        atomicAdd(&acc[u.w & (BSIZE - 1u)], __uint_as_float(u.w & ~(unsigned)(BSIZE - 1)));
    }
    for (unsigned i = (nq << 2) + tid; i < cnt; i += 1024) {
        unsigned u = base[i];
        atomicAdd(&acc[u & (BSIZE - 1u)], __uint_as_float(u & ~(unsigned)(BSIZE - 1)));
    }

    unsigned sn = gcur[nb];               // spill count: 0 in practice (1 load)
    if (sn) {
        if (sn > SPILL_CAP) sn = SPILL_CAP;
        for (unsigned i = tid; i < sn; i += 1024) {
            uint2 e = spill[i];
            if ((int)(e.x >> BSHIFT) == b)
                atomicAdd(&acc[e.x & (BSIZE - 1u)], __uint_as_float(e.y));
        }
    }
    __syncthreads();

    int i0 = (b << BSHIFT) + tid;
    if (i0 < n_nodes)
        out[i0] = (-v[i0] + acc[tid] + stim[i0] + vrest[i0]) / tau[i0];
}

// ---------------- fallback (agent-scope atomics, always correct) ----------------

__global__ void node_pre_kernel(const float* __restrict__ v,
                                const int* __restrict__ ntype,
                                const float* __restrict__ tp,
                                float* __restrict__ g,
                                float* __restrict__ msg, int n) {
    int i = blockIdx.x * blockDim.x + threadIdx.x;
    if (i < n) {
        float x = v[i];
        x = x > 0.0f ? x : 0.0f;
        g[i] = x * tp[ntype[i]];
        msg[i] = 0.0f;
    }
}

__global__ void edge_scatter_kernel(const int* __restrict__ src,
                                    const int* __restrict__ dst,
                                    const float* __restrict__ w,
                                    const float* __restrict__ g,
                                    float* __restrict__ msg, int n_vec) {
    int i = blockIdx.x * blockDim.x + threadIdx.x;
    if (i < n_vec) {
        int4 s = ((const int4*)src)[i];
        int4 d = ((const int4*)dst)[i];
        float4 wv = ((const float4*)w)[i];
        atomicAdd(&msg[d.x], wv.x * g[s.x]);
        atomicAdd(&msg[d.y], wv.y * g[s.y]);
        atomicAdd(&msg[d.z], wv.z * g[s.z]);
        atomicAdd(&msg[d.w], wv.w * g[s.w]);
    }
}

__global__ void edge_scatter_tail(const int* __restrict__ src,
                                  const int* __restrict__ dst,
                                  const float* __restrict__ w,
                                  const float* __restrict__ g,
                                  float* __restrict__ msg,
                                  int start, int n_edges) {
    int i = start + blockIdx.x * blockDim.x + threadIdx.x;
    if (i < n_edges) atomicAdd(&msg[dst[i]], w[i] * g[src[i]]);
}

__global__ void node_post_kernel(const float* __restrict__ v,
                                 const float* __restrict__ msg,
                                 const float* __restrict__ stim,
                                 const float* __restrict__ vrest,
                                 const float* __restrict__ tau,
                                 float* __restrict__ out, int n) {
    int i = blockIdx.x * blockDim.x + threadIdx.x;
    if (i < n)
        out[i] = (-v[i] + msg[i] + stim[i] + vrest[i]) / tau[i];
}

// ---------------- launch ----------------

extern "C" void kernel_launch(void* const* d_in, const int* in_sizes, int n_in,
                              void* d_out, int out_size, void* d_ws, size_t ws_size,
                              hipStream_t stream) {
    const float* voltage  = (const float*)d_in[0];
    const float* stimulus = (const float*)d_in[1];
    const int*   ntype    = (const int*)d_in[2];
    const int*   edge_idx = (const int*)d_in[3];
    const float* w        = (const float*)d_in[4];
    const float* vrest    = (const float*)d_in[5];
    const float* tau      = (const float*)d_in[6];
    const float* tp       = (const float*)d_in[7];
    float* out = (float*)d_out;

    const int n_nodes = in_sizes[0];
    const int n_edges = in_sizes[4];
    const int* src = edge_idx;
    const int* dst = edge_idx + n_edges;

    const int B = 256;
    const int G = n_edges / 4;
    int nblk = (G + GPB - 1) / GPB;
    if (nblk < 1) nblk = 1;
    const int nb = (n_nodes + BSIZE - 1) / BSIZE;

    // per-bucket capacity: mean load + 2048 (~11 sigma for uniform random dst)
    int cap = (int)(((long long)n_edges * BSIZE) / (long long)(n_nodes > 0 ? n_nodes : 1)) + 2048;
    cap = (cap + 3) & ~3;   // keep uint4 alignment of bucket bases

    auto align256 = [](size_t x) { return (x + 255) & ~(size_t)255; };
    size_t g_off     = 0;
    size_t gcur_off  = align256(g_off + (size_t)n_nodes * 4);
    size_t spill_off = align256(gcur_off + (size_t)(nb + 1) * 4);
    size_t bb_off    = align256(spill_off + (size_t)SPILL_CAP * 8);
    size_t need      = align256(bb_off + (size_t)nb * (size_t)cap * 4);

    if (nb < NBMAX && ws_size >= need) {
        float*    g         = (float*)((char*)d_ws + g_off);
        unsigned* gcur      = (unsigned*)((char*)d_ws + gcur_off);
        uint2*    spill     = (uint2*)((char*)d_ws + spill_off);
        unsigned* bucketbuf = (unsigned*)((char*)d_ws + bb_off);

        pre_g_kernel<<<(n_nodes + B - 1) / B, B, 0, stream>>>(
            voltage, ntype, tp, g, gcur, n_nodes, nb);
        scatter_kernel<<<nblk, 1024, 0, stream>>>(
            src, dst, w, g, bucketbuf, gcur, spill, G, n_edges, nblk, nb, cap);
        accum_kernel<<<nb, 1024, 0, stream>>>(
            bucketbuf, gcur, spill, voltage, stimulus, vrest, tau, out,
            n_nodes, nb, cap);
    } else {
        float* g   = (float*)d_ws;
        float* msg = (float*)d_ws + n_nodes;
        node_pre_kernel<<<(n_nodes + B - 1) / B, B, 0, stream>>>(
            voltage, ntype, tp, g, msg, n_nodes);
        if (G > 0)
            edge_scatter_kernel<<<(G + B - 1) / B, B, 0, stream>>>(
                src, dst, w, g, msg, G);
        if (G * 4 < n_edges) {
            int rem = n_edges - G * 4;
            edge_scatter_tail<<<(rem + B - 1) / B, B, 0, stream>>>(
                src, dst, w, g, msg, G * 4, n_edges);
        }
        node_post_kernel<<<(n_nodes + B - 1) / B, B, 0, stream>>>(
            voltage, msg, stimulus, vrest, tau, out, n_nodes);
    }
}